// Round 4
// baseline (1080.297 us; speedup 1.0000x reference)
//
#include <hip/hip_runtime.h>
#include <math.h>

namespace {

typedef __bf16 bf16x8 __attribute__((ext_vector_type(8)));
typedef float  f32x4  __attribute__((ext_vector_type(4)));

constexpr int B_      = 65536;
constexpr int OBS_DIM_= 85;
constexpr int NL_     = 5;
constexpr int NT_     = 10;
constexpr int HID_    = 64;
constexpr int NACT_   = 5;
constexpr float ALPHA_= 0.01f;

constexpr int ROWS_ = 64;     // rows per block (4 waves x 16-row MFMA tiles)
constexpr int BLK_  = 256;
constexpr int SOB_  = 104;    // A_obs LDS stride (elems): 208B/row -> 2-way bank alias (free)
constexpr int SXH_  = 72;     // A_x/A_h stride: 144B/row -> 2-way alias (free), 16B-aligned

__device__ __forceinline__ float leaky(float x)    { return x > 0.0f ? x : ALPHA_ * x; }
__device__ __forceinline__ float sigmoidf(float x) { return 1.0f / (1.0f + __expf(-x)); }
__device__ __forceinline__ float tanh_fast(float x){ return 1.0f - 2.0f / (__expf(2.0f * x) + 1.0f); }

// ---------------------------------------------------------------------------
// Prep (every launch): Wa = W@a (kills the (B,10,64)@(64,64) matmul),
// bf16 copies of w_ih, w_hh, and transposed+padded w_fc1 (K 90->96, zeros).
// d_ws layout: [0,512) Wa f32; [512,..) Wih bf16 192x64; Whh; Wfc1T 64x96.
// ---------------------------------------------------------------------------
__global__ void prep_kernel(const float* __restrict__ W, const float* __restrict__ a,
                            const float* __restrict__ w_ih, const float* __restrict__ w_hh,
                            const float* __restrict__ w_fc1, void* __restrict__ ws) {
  float* Wa   = (float*)ws;
  __bf16* ih  = (__bf16*)((char*)ws + 512);
  __bf16* hh  = ih + 192 * 64;
  __bf16* f1t = hh + 192 * 64;
  const int tid = blockIdx.x * 256 + threadIdx.x;
  if (blockIdx.x == 0 && threadIdx.x < 64) {
    const int i = threadIdx.x;
    float s1 = 0.0f, s2 = 0.0f;
    #pragma unroll
    for (int j = 0; j < 64; ++j) {
      float w = W[i * 64 + j];
      s1 += w * a[j];
      s2 += w * a[64 + j];
    }
    Wa[i] = s1;
    Wa[64 + i] = s2;
  }
  const int stride = gridDim.x * 256;
  for (int i = tid; i < 192 * 64; i += stride) {
    ih[i] = (__bf16)w_ih[i];
    hh[i] = (__bf16)w_hh[i];
  }
  for (int i = tid; i < 64 * 96; i += stride) {
    int n = i / 96, k = i - 96 * n;
    f1t[i] = (__bf16)(k < 90 ? w_fc1[k * 64 + n] : 0.0f);
  }
}

// Stage-1 for t in [T0,T1): lane owns 16 of 64 INF units (u0 = sub*16).
template <int T0, int T1>
__device__ __forceinline__ void stage1c(const float* __restrict__ wc,
                                        const float* __restrict__ bc,
                                        const __bf16* orow, int u0,
                                        const float* wa1, const float* wa2,
                                        float (&p1)[NT_], float (&p2)[NT_]) {
  float bb[16];
  #pragma unroll
  for (int j = 0; j < 16; ++j) bb[j] = bc[u0 + j];
  #pragma unroll
  for (int t = T0; t < T1; ++t) {
    float ov[8];
    #pragma unroll
    for (int f = 0; f < 8; ++f) {
      int j0 = t * 8 + f + 4;            // obs_in[i] = o[(i+4) mod 80]
      if (j0 >= 80) j0 -= 80;            // compile-time after unroll
      ov[f] = (float)orow[j0];
    }
    float z[16];
    #pragma unroll
    for (int j = 0; j < 16; ++j) z[j] = bb[j];
    #pragma unroll
    for (int f = 0; f < 8; ++f) {
      const float* wr = wc + f * 64 + u0;
      #pragma unroll
      for (int j = 0; j < 16; ++j) z[j] += ov[f] * wr[j];
    }
    float a1 = 0.0f, a2 = 0.0f;
    #pragma unroll
    for (int j = 0; j < 16; ++j) {
      float hm = leaky(z[j]);
      a1 += hm * wa1[j];
      a2 += hm * wa2[j];
    }
    p1[t] = a1; p2[t] = a2;
  }
}

// attention row r (runtime in [0,5)): returns hp3 for that row
__device__ __forceinline__ float attn_row(int r, const float* p1, const float* p2,
                                          const float* colm, const float* cols_,
                                          const float* __restrict__ w_o1, const float* __restrict__ b_o1,
                                          const float* __restrict__ w_o2, const float* __restrict__ b_o2,
                                          const float* __restrict__ w_o3, const float* __restrict__ b_o3) {
  float wh1_r = p1[0], wh2_r = p2[0];    // select chain: no dynamic reg index
  if (r == 1) { wh1_r = p1[1]; wh2_r = p2[1]; }
  if (r == 2) { wh1_r = p1[2]; wh2_r = p2[2]; }
  if (r == 3) { wh1_r = p1[3]; wh2_r = p2[3]; }
  if (r == 4) { wh1_r = p1[4]; wh2_r = p2[4]; }
  float att[NT_];
  {
    float ev[NL_], m = -1e30f;
    #pragma unroll
    for (int j = 0; j < NL_; ++j) { ev[j] = leaky(wh1_r + p2[NL_ + j]); m = fmaxf(m, ev[j]); }
    float s = 0.0f;
    #pragma unroll
    for (int j = 0; j < NL_; ++j) { float e = __expf(ev[j] - m); att[j] = e; s += e; }
    float inv = 1.0f / s;
    #pragma unroll
    for (int j = 0; j < NL_; ++j) att[j] *= inv;
    #pragma unroll
    for (int jj = 0; jj < NL_; ++jj) {
      float e = leaky(p1[NL_ + jj] + wh2_r);
      att[NL_ + jj] = __expf(e - colm[jj]) / cols_[jj];
    }
  }
  float h1v[32];
  #pragma unroll
  for (int c = 0; c < 32; ++c) {
    float z = b_o1[c];
    #pragma unroll
    for (int k = 0; k < NT_; ++k) z += att[k] * w_o1[k * 32 + c];
    h1v[c] = leaky(z);
  }
  float h2v[16];
  #pragma unroll
  for (int c = 0; c < 16; ++c) {
    float z = b_o2[c];
    #pragma unroll
    for (int k = 0; k < 32; ++k) z += h1v[k] * w_o2[k * 16 + c];
    h2v[c] = leaky(z);
  }
  float z3 = b_o3[0];
  #pragma unroll
  for (int k = 0; k < 16; ++k) z3 += h2v[k] * w_o3[k];
  return leaky(z3);
}

__global__ __launch_bounds__(BLK_) void atom_rnn_fused(
    const float* __restrict__ obs, const float* __restrict__ hidden,
    const float* __restrict__ w_in0, const float* __restrict__ b_in0,
    const float* __restrict__ w_in1, const float* __restrict__ b_in1,
    const float* __restrict__ w_in2, const float* __restrict__ b_in2,
    const float* __restrict__ w_o1, const float* __restrict__ b_o1,
    const float* __restrict__ w_o2, const float* __restrict__ b_o2,
    const float* __restrict__ w_o3, const float* __restrict__ b_o3,
    const float* __restrict__ b_fc1,
    const float* __restrict__ b_ih, const float* __restrict__ b_hh,
    const float* __restrict__ w_fc2, const float* __restrict__ b_fc2,
    const void* __restrict__ wsv,
    float* __restrict__ q_out, float* __restrict__ h_out) {

  __shared__ __align__(16) __bf16 A_obs[ROWS_ * SOB_];  // 13312 B
  __shared__ __align__(16) __bf16 A_x[ROWS_ * SXH_];    //  9216 B
  __shared__ __align__(16) __bf16 A_h[ROWS_ * SXH_];    //  9216 B

  const int tid  = threadIdx.x;
  const int wv   = tid >> 6;            // wave id 0..3
  const int lane = tid & 63;
  const int l    = lane & 15;
  const int quad = lane >> 4;
  const int r0   = wv * 16;             // wave's 16-row tile within block
  const long gr0 = (long)blockIdx.x * ROWS_;

  const float*  Wa  = (const float*)wsv;
  const __bf16* Wih = (const __bf16*)((const char*)wsv + 512);
  const __bf16* Whh = Wih + 192 * 64;
  const __bf16* Wf1 = Whh + 192 * 64;

  // ---- phase 0: wave-local staging (no __syncthreads anywhere) ----
  {
    const float* src = obs + (gr0 + r0) * OBS_DIM_;
    for (int it = lane; it < 16 * OBS_DIM_; it += 64) {
      int rr = it / OBS_DIM_; int cc = it - rr * OBS_DIM_;
      A_obs[(r0 + rr) * SOB_ + cc] = (__bf16)src[it];
    }
    const float* hsrc = hidden + (gr0 + r0) * HID_;
    for (int it = lane; it < 16 * HID_; it += 64) {
      int rr = it >> 6; int cc = it & 63;
      A_h[(r0 + rr) * SXH_ + cc] = (__bf16)hsrc[it];
    }
    for (int it = lane; it < 16 * 11; it += 64) {   // zero K-pad cols 85..95
      int rr = it / 11; int cc = it - rr * 11;
      A_obs[(r0 + rr) * SOB_ + 85 + cc] = (__bf16)0.0f;
    }
  }

  // ---- front phase: 4 lanes per row, wave-local rows r0..r0+15 ----
  const int sub   = lane & 3;
  const int row_l = r0 + (lane >> 2);
  const __bf16* orow = &A_obs[row_l * SOB_];
  const int u0 = sub * 16;

  float p1[NT_], p2[NT_];
  {
    float wa1[16], wa2[16];
    #pragma unroll
    for (int j = 0; j < 16; ++j) { wa1[j] = Wa[u0 + j]; wa2[j] = Wa[64 + u0 + j]; }
    stage1c<0, 5>(w_in0, b_in0, orow, u0, wa1, wa2, p1, p2);
    stage1c<5, 9>(w_in1, b_in1, orow, u0, wa1, wa2, p1, p2);
    stage1c<9, 10>(w_in2, b_in2, orow, u0, wa1, wa2, p1, p2);
  }
  #pragma unroll
  for (int m = 1; m < 4; m <<= 1) {
    #pragma unroll
    for (int t = 0; t < NT_; ++t) {
      p1[t] += __shfl_xor(p1[t], m, 64);
      p2[t] += __shfl_xor(p2[t], m, 64);
    }
  }

  float colm[NL_], cols_[NL_];
  #pragma unroll
  for (int jj = 0; jj < NL_; ++jj) {
    float ev[NL_], m = -1e30f;
    #pragma unroll
    for (int k = 0; k < NL_; ++k) { ev[k] = leaky(p1[NL_ + jj] + p2[k]); m = fmaxf(m, ev[k]); }
    float s = 0.0f;
    #pragma unroll
    for (int k = 0; k < NL_; ++k) s += __expf(ev[k] - m);
    colm[jj] = m; cols_[jj] = s;
  }

  float hp_a = attn_row(sub, p1, p2, colm, cols_, w_o1, b_o1, w_o2, b_o2, w_o3, b_o3);
  float hp_b = 0.0f;
  if (sub == 0)
    hp_b = attn_row(4, p1, p2, colm, cols_, w_o1, b_o1, w_o2, b_o2, w_o3, b_o3);

  float obs_out[NL_];
  {
    const int g = lane & ~3;
    float hp[NL_];
    #pragma unroll
    for (int k = 0; k < 4; ++k) hp[k] = __shfl(hp_a, g + k, 64);
    hp[4] = __shfl(hp_b, g, 64);
    float m5 = hp[0];
    #pragma unroll
    for (int j = 1; j < NL_; ++j) m5 = fmaxf(m5, hp[j]);
    float s = 0.0f;
    #pragma unroll
    for (int j = 0; j < NL_; ++j) { obs_out[j] = __expf(hp[j] - m5); s += obs_out[j]; }
    float inv = 1.0f / s;
    #pragma unroll
    for (int j = 0; j < NL_; ++j) obs_out[j] *= inv;
  }
  {
    float ow = obs_out[0];               // select chain, no dynamic index
    if (sub == 1) ow = obs_out[1];
    if (sub == 2) ow = obs_out[2];
    if (sub == 3) ow = obs_out[3];
    A_obs[row_l * SOB_ + 85 + sub] = (__bf16)ow;
    if (sub == 0) A_obs[row_l * SOB_ + 89] = (__bf16)obs_out[4];
  }

  // ---- MFMA phase (wave-local: reads only rows this wave wrote) ----
  const f32x4 zero4 = {0.0f, 0.0f, 0.0f, 0.0f};

  // fc1: C[16x64] = A_obs[16x96] @ Wf1^T tiles
  f32x4 cx[4];
  #pragma unroll
  for (int nt = 0; nt < 4; ++nt) cx[nt] = zero4;
  #pragma unroll
  for (int ks = 0; ks < 3; ++ks) {
    bf16x8 af = *(const bf16x8*)&A_obs[(r0 + l) * SOB_ + ks * 32 + quad * 8];
    #pragma unroll
    for (int nt = 0; nt < 4; ++nt) {
      bf16x8 bf = *(const bf16x8*)&Wf1[(nt * 16 + l) * 96 + ks * 32 + quad * 8];
      cx[nt] = __builtin_amdgcn_mfma_f32_16x16x32_bf16(af, bf, cx[nt], 0, 0, 0);
    }
  }
  #pragma unroll
  for (int nt = 0; nt < 4; ++nt) {
    float bias = b_fc1[nt * 16 + l];
    #pragma unroll
    for (int rg = 0; rg < 4; ++rg) {
      float xv = fmaxf(cx[nt][rg] + bias, 0.0f);
      A_x[(r0 + quad * 4 + rg) * SXH_ + nt * 16 + l] = (__bf16)xv;
    }
  }

  // GRU GEMMs: gi/gh fused. rz tiles share accumulators; n-gate split.
  bf16x8 ax[2], ah[2];
  #pragma unroll
  for (int ks = 0; ks < 2; ++ks) {
    ax[ks] = *(const bf16x8*)&A_x[(r0 + l) * SXH_ + ks * 32 + quad * 8];
    ah[ks] = *(const bf16x8*)&A_h[(r0 + l) * SXH_ + ks * 32 + quad * 8];
  }
  f32x4 crz[8], cni[4], cnh[4];
  #pragma unroll
  for (int nt = 0; nt < 8; ++nt) crz[nt] = zero4;
  #pragma unroll
  for (int nt = 0; nt < 4; ++nt) { cni[nt] = zero4; cnh[nt] = zero4; }
  #pragma unroll
  for (int nt = 0; nt < 8; ++nt) {
    #pragma unroll
    for (int ks = 0; ks < 2; ++ks) {
      bf16x8 bi = *(const bf16x8*)&Wih[(nt * 16 + l) * 64 + ks * 32 + quad * 8];
      crz[nt] = __builtin_amdgcn_mfma_f32_16x16x32_bf16(ax[ks], bi, crz[nt], 0, 0, 0);
      bf16x8 bh = *(const bf16x8*)&Whh[(nt * 16 + l) * 64 + ks * 32 + quad * 8];
      crz[nt] = __builtin_amdgcn_mfma_f32_16x16x32_bf16(ah[ks], bh, crz[nt], 0, 0, 0);
    }
  }
  #pragma unroll
  for (int nt = 0; nt < 4; ++nt) {
    #pragma unroll
    for (int ks = 0; ks < 2; ++ks) {
      bf16x8 bi = *(const bf16x8*)&Wih[(128 + nt * 16 + l) * 64 + ks * 32 + quad * 8];
      cni[nt] = __builtin_amdgcn_mfma_f32_16x16x32_bf16(ax[ks], bi, cni[nt], 0, 0, 0);
      bf16x8 bh = *(const bf16x8*)&Whh[(128 + nt * 16 + l) * 64 + ks * 32 + quad * 8];
      cnh[nt] = __builtin_amdgcn_mfma_f32_16x16x32_bf16(ah[ks], bh, cnh[nt], 0, 0, 0);
    }
  }

  // ---- epilogue: gates, h_out, q (C layout: row = quad*4+rg, col = t*16+l) ----
  const long grow = gr0 + r0 + quad * 4;
  float qp[4][NACT_];
  #pragma unroll
  for (int rg = 0; rg < 4; ++rg)
    #pragma unroll
    for (int c = 0; c < NACT_; ++c) qp[rg][c] = 0.0f;

  #pragma unroll
  for (int t = 0; t < 4; ++t) {
    const int ur = t * 16 + l;
    float br  = b_ih[ur] + b_hh[ur];
    float bz  = b_ih[64 + ur] + b_hh[64 + ur];
    float bin = b_ih[128 + ur], bhn = b_hh[128 + ur];
    float w0 = w_fc2[ur * 5 + 0], w1 = w_fc2[ur * 5 + 1], w2 = w_fc2[ur * 5 + 2];
    float w3 = w_fc2[ur * 5 + 3], w4 = w_fc2[ur * 5 + 4];
    #pragma unroll
    for (int rg = 0; rg < 4; ++rg) {
      float rr = sigmoidf(crz[t][rg] + br);
      float zz = sigmoidf(crz[4 + t][rg] + bz);
      float nn = tanh_fast(cni[t][rg] + bin + rr * (cnh[t][rg] + bhn));
      float hold = hidden[(grow + rg) * HID_ + ur];
      float hn = (1.0f - zz) * nn + zz * hold;
      h_out[(grow + rg) * HID_ + ur] = hn;
      qp[rg][0] += hn * w0;
      qp[rg][1] += hn * w1;
      qp[rg][2] += hn * w2;
      qp[rg][3] += hn * w3;
      qp[rg][4] += hn * w4;
    }
  }
  #pragma unroll
  for (int m = 1; m < 16; m <<= 1) {
    #pragma unroll
    for (int rg = 0; rg < 4; ++rg)
      #pragma unroll
      for (int c = 0; c < NACT_; ++c) qp[rg][c] += __shfl_xor(qp[rg][c], m, 64);
  }
  if (l < NACT_) {
    #pragma unroll
    for (int rg = 0; rg < 4; ++rg) {
      float qv = qp[rg][0];
      if (l == 1) qv = qp[rg][1];
      if (l == 2) qv = qp[rg][2];
      if (l == 3) qv = qp[rg][3];
      if (l == 4) qv = qp[rg][4];
      q_out[(grow + rg) * NACT_ + l] = qv + b_fc2[l];
    }
  }
}

}  // namespace

extern "C" void kernel_launch(void* const* d_in, const int* in_sizes, int n_in,
                              void* d_out, int out_size, void* d_ws, size_t ws_size,
                              hipStream_t stream) {
  const float* obs    = (const float*)d_in[0];
  const float* hidden = (const float*)d_in[1];
  const float* w_in0  = (const float*)d_in[2];
  const float* b_in0  = (const float*)d_in[3];
  const float* w_in1  = (const float*)d_in[4];
  const float* b_in1  = (const float*)d_in[5];
  const float* w_in2  = (const float*)d_in[6];
  const float* b_in2  = (const float*)d_in[7];
  const float* W      = (const float*)d_in[8];
  const float* a      = (const float*)d_in[9];
  const float* w_o1   = (const float*)d_in[10];
  const float* b_o1   = (const float*)d_in[11];
  const float* w_o2   = (const float*)d_in[12];
  const float* b_o2   = (const float*)d_in[13];
  const float* w_o3   = (const float*)d_in[14];
  const float* b_o3   = (const float*)d_in[15];
  const float* w_fc1  = (const float*)d_in[16];
  const float* b_fc1  = (const float*)d_in[17];
  const float* w_ih   = (const float*)d_in[18];
  const float* w_hh   = (const float*)d_in[19];
  const float* b_ih   = (const float*)d_in[20];
  const float* b_hh   = (const float*)d_in[21];
  const float* w_fc2  = (const float*)d_in[22];
  const float* b_fc2  = (const float*)d_in[23];

  float* q_out = (float*)d_out;                  // (B, 5) flat
  float* h_out = q_out + (long)B_ * NACT_;       // (B, 64) flat

  prep_kernel<<<48, 256, 0, stream>>>(W, a, w_ih, w_hh, w_fc1, d_ws);
  atom_rnn_fused<<<B_ / ROWS_, BLK_, 0, stream>>>(
      obs, hidden, w_in0, b_in0, w_in1, b_in1, w_in2, b_in2,
      w_o1, b_o1, w_o2, b_o2, w_o3, b_o3, b_fc1,
      b_ih, b_hh, w_fc2, b_fc2, d_ws, q_out, h_out);
}

// Round 5
// 327.355 us; speedup vs baseline: 3.3001x; 3.3001x over previous
//
#include <hip/hip_runtime.h>
#include <math.h>

namespace {

typedef __bf16 bf16x8 __attribute__((ext_vector_type(8)));
typedef float  f32x4  __attribute__((ext_vector_type(4)));

constexpr int B_      = 65536;
constexpr int OBS_DIM_= 85;
constexpr int NL_     = 5;
constexpr int NT_     = 10;
constexpr int HID_    = 64;
constexpr int NACT_   = 5;
constexpr float ALPHA_= 0.01f;

__device__ __forceinline__ float leaky(float x)    { return x > 0.0f ? x : ALPHA_ * x; }
__device__ __forceinline__ float sigmoidf(float x) { return 1.0f / (1.0f + __expf(-x)); }
__device__ __forceinline__ float tanh_fast(float x){ return 1.0f - 2.0f / (__expf(2.0f * x) + 1.0f); }

// ---------------------------------------------------------------------------
// Prep: Wa = W@a  ((h_mix@W)@a == h_mix@(W@a): kills the 64x64 matmul), plus
// bf16 weights for the MFMA kernel. ws: [0,512) Wa f32; Wih; Whh; Wf1T(64x96).
// ---------------------------------------------------------------------------
__global__ void prep_kernel(const float* __restrict__ W, const float* __restrict__ a,
                            const float* __restrict__ w_ih, const float* __restrict__ w_hh,
                            const float* __restrict__ w_fc1, void* __restrict__ ws) {
  float* Wa   = (float*)ws;
  __bf16* ih  = (__bf16*)((char*)ws + 512);
  __bf16* hh  = ih + 192 * 64;
  __bf16* f1t = hh + 192 * 64;
  const int tid = blockIdx.x * 256 + threadIdx.x;
  if (blockIdx.x == 0 && threadIdx.x < 64) {
    const int i = threadIdx.x;
    float s1 = 0.0f, s2 = 0.0f;
    #pragma unroll
    for (int j = 0; j < 64; ++j) {
      float w = W[i * 64 + j];
      s1 += w * a[j];
      s2 += w * a[64 + j];
    }
    Wa[i] = s1;
    Wa[64 + i] = s2;
  }
  const int stride = gridDim.x * 256;
  for (int i = tid; i < 192 * 64; i += stride) {
    ih[i] = (__bf16)w_ih[i];
    hh[i] = (__bf16)w_hh[i];
  }
  for (int i = tid; i < 64 * 96; i += stride) {
    int n = i / 96, k = i - 96 * n;
    f1t[i] = (__bf16)(k < 90 ? w_fc1[k * 64 + n] : 0.0f);
  }
}

// ======================= FRONT KERNEL =======================
constexpr int FROWS_ = 32;    // rows per block, 8 lanes cooperate per row
constexpr int SOBS_  = 88;    // f32 row stride: 352B -> 16B aligned, 2-way bank alias (free)

// stage1 for t in [T0,T1): lane owns units u0..u0+7. Weights hoisted to regs.
template <int T0, int T1>
__device__ __forceinline__ void stage1_cls(const float (*wT)[9], const float* bin,
                                           const float* orow, int u0,
                                           const float* wa1, const float* wa2,
                                           float (&p1)[NT_], float (&p2)[NT_]) {
  float w[8][8];
  #pragma unroll
  for (int j = 0; j < 8; ++j)
    #pragma unroll
    for (int f = 0; f < 8; ++f) w[j][f] = wT[u0 + j][f];
  float bb[8];
  #pragma unroll
  for (int j = 0; j < 8; ++j) bb[j] = bin[u0 + j];
  #pragma unroll
  for (int t = T0; t < T1; ++t) {
    const int ia = t * 8 + 4;            // f=0..3: never wraps (8t+7 <= 79)
    const int ib = (t * 8 + 8) % 80;     // f=4..7: wraps only at t=9 -> 0..3
    f32x4 oa = *(const f32x4*)&orow[ia];
    f32x4 ob = *(const f32x4*)&orow[ib];
    float a1 = 0.0f, a2 = 0.0f;
    #pragma unroll
    for (int j = 0; j < 8; ++j) {
      float z = bb[j];
      z += oa[0] * w[j][0] + oa[1] * w[j][1] + oa[2] * w[j][2] + oa[3] * w[j][3];
      z += ob[0] * w[j][4] + ob[1] * w[j][5] + ob[2] * w[j][6] + ob[3] * w[j][7];
      float hm = leaky(z);
      a1 += hm * wa1[j];
      a2 += hm * wa2[j];
    }
    p1[t] = a1; p2[t] = a2;
  }
}

// attention row r in [0,5): full 10->32->16->1 MLP. Weights are wave-uniform
// global reads -> scalar s_load pipe (free of VALU/LDS issue).
__device__ __forceinline__ float attn_row(int r, const float* p1, const float* p2,
                                          const float* colm, const float* cols_,
                                          const float* __restrict__ w_o1, const float* __restrict__ b_o1,
                                          const float* __restrict__ w_o2, const float* __restrict__ b_o2,
                                          const float* __restrict__ w_o3, const float* __restrict__ b_o3) {
  float wh1_r = p1[0], wh2_r = p2[0];
  if (r == 1) { wh1_r = p1[1]; wh2_r = p2[1]; }
  if (r == 2) { wh1_r = p1[2]; wh2_r = p2[2]; }
  if (r == 3) { wh1_r = p1[3]; wh2_r = p2[3]; }
  if (r == 4) { wh1_r = p1[4]; wh2_r = p2[4]; }
  float att[NT_];
  {
    float ev[NL_], m = -1e30f;
    #pragma unroll
    for (int j = 0; j < NL_; ++j) { ev[j] = leaky(wh1_r + p2[NL_ + j]); m = fmaxf(m, ev[j]); }
    float s = 0.0f;
    #pragma unroll
    for (int j = 0; j < NL_; ++j) { float e = __expf(ev[j] - m); att[j] = e; s += e; }
    float inv = 1.0f / s;
    #pragma unroll
    for (int j = 0; j < NL_; ++j) att[j] *= inv;
    #pragma unroll
    for (int jj = 0; jj < NL_; ++jj) {
      float e = leaky(p1[NL_ + jj] + wh2_r);
      att[NL_ + jj] = __expf(e - colm[jj]) / cols_[jj];
    }
  }
  float h1v[32];
  #pragma unroll
  for (int c = 0; c < 32; ++c) {
    float z = b_o1[c];
    #pragma unroll
    for (int k = 0; k < NT_; ++k) z += att[k] * w_o1[k * 32 + c];
    h1v[c] = leaky(z);
  }
  float h2v[16];
  #pragma unroll
  for (int c = 0; c < 16; ++c) {
    float z = b_o2[c];
    #pragma unroll
    for (int k = 0; k < 32; ++k) z += h1v[k] * w_o2[k * 16 + c];
    h2v[c] = leaky(z);
  }
  float z3 = b_o3[0];
  #pragma unroll
  for (int k = 0; k < 16; ++k) z3 += h2v[k] * w_o3[k];
  return leaky(z3);
}

__global__ __launch_bounds__(256, 4) void front_kernel(
    const float* __restrict__ obs,
    const float* __restrict__ w_in0, const float* __restrict__ b_in0,
    const float* __restrict__ w_in1, const float* __restrict__ b_in1,
    const float* __restrict__ w_in2, const float* __restrict__ b_in2,
    const float* __restrict__ w_o1, const float* __restrict__ b_o1,
    const float* __restrict__ w_o2, const float* __restrict__ b_o2,
    const float* __restrict__ w_o3, const float* __restrict__ b_o3,
    const float* __restrict__ Wa,
    float* __restrict__ out5) {

  __shared__ __align__(16) float s_obs[FROWS_][SOBS_];
  __shared__ float s_wT[3][64][9];   // [class][unit][feat], stride 9 -> 2-way alias (free)
  __shared__ float s_bin[3][64];

  const int tid = threadIdx.x;
  const long gr0 = (long)blockIdx.x * FROWS_;

  // stage obs cols 0..79 (stage-1 uses only the first 80)
  {
    const float* src = obs + gr0 * OBS_DIM_;
    for (int idx = tid; idx < FROWS_ * 80; idx += 256) {
      int r = idx / 80, c = idx - 80 * r;
      s_obs[r][c] = src[r * OBS_DIM_ + c];
    }
  }
  // stage transposed stage-1 weights + biases
  {
    #pragma unroll
    for (int k = 0; k < 6; ++k) {
      const int c = k >> 1;
      const int rem = ((k & 1) << 8) + tid;   // 0..511
      const int f = rem >> 6, i = rem & 63;
      const float* wc = (c == 0) ? w_in0 : (c == 1) ? w_in1 : w_in2;
      s_wT[c][i][f] = wc[f * 64 + i];
    }
    if (tid < 192) {
      const int c = tid >> 6, i = tid & 63;
      const float* bc = (c == 0) ? b_in0 : (c == 1) ? b_in1 : b_in2;
      s_bin[c][i] = bc[i];
    }
  }
  __syncthreads();

  const int lane = tid & 63;
  const int sub  = lane & 7;
  const int rloc = ((tid >> 6) << 3) + (lane >> 3);
  const int u0   = sub * 8;
  const float* orow = s_obs[rloc];

  float wa1[8], wa2[8];
  #pragma unroll
  for (int j = 0; j < 8; ++j) { wa1[j] = Wa[u0 + j]; wa2[j] = Wa[64 + u0 + j]; }

  float p1[NT_], p2[NT_];
  stage1_cls<0, 5>(s_wT[0], s_bin[0], orow, u0, wa1, wa2, p1, p2);
  stage1_cls<5, 9>(s_wT[1], s_bin[1], orow, u0, wa1, wa2, p1, p2);
  stage1_cls<9, 10>(s_wT[2], s_bin[2], orow, u0, wa1, wa2, p1, p2);

  #pragma unroll
  for (int m = 1; m < 8; m <<= 1) {
    #pragma unroll
    for (int t = 0; t < NT_; ++t) {
      p1[t] += __shfl_xor(p1[t], m, 64);
      p2[t] += __shfl_xor(p2[t], m, 64);
    }
  }

  float colm[NL_], cols_[NL_];
  #pragma unroll
  for (int jj = 0; jj < NL_; ++jj) {
    float ev[NL_], m = -1e30f;
    #pragma unroll
    for (int k = 0; k < NL_; ++k) { ev[k] = leaky(p1[NL_ + jj] + p2[k]); m = fmaxf(m, ev[k]); }
    float s = 0.0f;
    #pragma unroll
    for (int k = 0; k < NL_; ++k) s += __expf(ev[k] - m);
    colm[jj] = m; cols_[jj] = s;
  }

  float hp_local = 0.0f;
  if (sub < NL_)
    hp_local = attn_row(sub, p1, p2, colm, cols_, w_o1, b_o1, w_o2, b_o2, w_o3, b_o3);

  // gather hp from lanes 0..4 of my 8-lane group, softmax
  const int g = lane & ~7;
  float hp[NL_];
  #pragma unroll
  for (int k = 0; k < NL_; ++k) hp[k] = __shfl(hp_local, g + k, 64);
  float m5 = hp[0];
  #pragma unroll
  for (int j = 1; j < NL_; ++j) m5 = fmaxf(m5, hp[j]);
  float ex[NL_], ssum = 0.0f;
  #pragma unroll
  for (int j = 0; j < NL_; ++j) { ex[j] = __expf(hp[j] - m5); ssum += ex[j]; }
  const float sinv = 1.0f / ssum;

  if (sub < NL_) {
    float ow = ex[0];
    if (sub == 1) ow = ex[1];
    if (sub == 2) ow = ex[2];
    if (sub == 3) ow = ex[3];
    if (sub == 4) ow = ex[4];
    out5[(gr0 + rloc) * NL_ + sub] = ow * sinv;
  }
}

// ======================= GEMM KERNEL (round-4 validated MFMA phase) =======================
constexpr int ROWS_ = 64;     // 4 waves x 16-row tiles
constexpr int SOB_  = 104;    // bf16 stride: 208B -> 2-way alias (free)
constexpr int SXH_  = 72;     // bf16 stride: 144B -> 2-way alias (free), 16B aligned

__global__ __launch_bounds__(256, 4) void gemm_kernel(
    const float* __restrict__ obs, const float* __restrict__ hidden,
    const float* __restrict__ b_fc1,
    const float* __restrict__ b_ih, const float* __restrict__ b_hh,
    const float* __restrict__ w_fc2, const float* __restrict__ b_fc2,
    const void* __restrict__ wsv,
    float* q5,                       // ALIASED: obs_out (read) then q (write)
    float* __restrict__ h_out) {

  __shared__ __align__(16) __bf16 A_obs[ROWS_ * SOB_];
  __shared__ __align__(16) __bf16 A_x[ROWS_ * SXH_];
  __shared__ __align__(16) __bf16 A_h[ROWS_ * SXH_];

  const int tid  = threadIdx.x;
  const int wv   = tid >> 6;
  const int lane = tid & 63;
  const int l    = lane & 15;
  const int quad = lane >> 4;
  const int r0   = wv * 16;
  const long gr0 = (long)blockIdx.x * ROWS_;

  const __bf16* Wih = (const __bf16*)((const char*)wsv + 512);
  const __bf16* Whh = Wih + 192 * 64;
  const __bf16* Wf1 = Whh + 192 * 64;

  // ---- wave-local staging (no __syncthreads in this kernel) ----
  {
    const float* src = obs + (gr0 + r0) * OBS_DIM_;
    for (int it = lane; it < 16 * OBS_DIM_; it += 64) {
      int rr = it / OBS_DIM_; int cc = it - rr * OBS_DIM_;
      A_obs[(r0 + rr) * SOB_ + cc] = (__bf16)src[it];
    }
    const float* o5 = q5 + (gr0 + r0) * NL_;
    for (int it = lane; it < 16 * NL_; it += 64) {
      int rr = it / NL_; int cc = it - rr * NL_;
      A_obs[(r0 + rr) * SOB_ + 85 + cc] = (__bf16)o5[it];
    }
    for (int it = lane; it < 16 * 6; it += 64) {    // zero K-pad cols 90..95
      int rr = it / 6; int cc = it - rr * 6;
      A_obs[(r0 + rr) * SOB_ + 90 + cc] = (__bf16)0.0f;
    }
    const float* hsrc = hidden + (gr0 + r0) * HID_;
    for (int it = lane; it < 16 * HID_; it += 64) {
      int rr = it >> 6; int cc = it & 63;
      A_h[(r0 + rr) * SXH_ + cc] = (__bf16)hsrc[it];
    }
  }

  const f32x4 zero4 = {0.0f, 0.0f, 0.0f, 0.0f};

  // fc1: C[16x64] = A_obs[16x96] @ Wf1T
  f32x4 cx[4];
  #pragma unroll
  for (int nt = 0; nt < 4; ++nt) cx[nt] = zero4;
  #pragma unroll
  for (int ks = 0; ks < 3; ++ks) {
    bf16x8 af = *(const bf16x8*)&A_obs[(r0 + l) * SOB_ + ks * 32 + quad * 8];
    #pragma unroll
    for (int nt = 0; nt < 4; ++nt) {
      bf16x8 bf = *(const bf16x8*)&Wf1[(nt * 16 + l) * 96 + ks * 32 + quad * 8];
      cx[nt] = __builtin_amdgcn_mfma_f32_16x16x32_bf16(af, bf, cx[nt], 0, 0, 0);
    }
  }
  #pragma unroll
  for (int nt = 0; nt < 4; ++nt) {
    float bias = b_fc1[nt * 16 + l];
    #pragma unroll
    for (int rg = 0; rg < 4; ++rg) {
      float xv = fmaxf(cx[nt][rg] + bias, 0.0f);
      A_x[(r0 + quad * 4 + rg) * SXH_ + nt * 16 + l] = (__bf16)xv;
    }
  }

  // GRU GEMMs
  bf16x8 ax[2], ah[2];
  #pragma unroll
  for (int ks = 0; ks < 2; ++ks) {
    ax[ks] = *(const bf16x8*)&A_x[(r0 + l) * SXH_ + ks * 32 + quad * 8];
    ah[ks] = *(const bf16x8*)&A_h[(r0 + l) * SXH_ + ks * 32 + quad * 8];
  }
  f32x4 crz[8], cni[4], cnh[4];
  #pragma unroll
  for (int nt = 0; nt < 8; ++nt) crz[nt] = zero4;
  #pragma unroll
  for (int nt = 0; nt < 4; ++nt) { cni[nt] = zero4; cnh[nt] = zero4; }
  #pragma unroll
  for (int nt = 0; nt < 8; ++nt) {
    #pragma unroll
    for (int ks = 0; ks < 2; ++ks) {
      bf16x8 bi = *(const bf16x8*)&Wih[(nt * 16 + l) * 64 + ks * 32 + quad * 8];
      crz[nt] = __builtin_amdgcn_mfma_f32_16x16x32_bf16(ax[ks], bi, crz[nt], 0, 0, 0);
      bf16x8 bh = *(const bf16x8*)&Whh[(nt * 16 + l) * 64 + ks * 32 + quad * 8];
      crz[nt] = __builtin_amdgcn_mfma_f32_16x16x32_bf16(ah[ks], bh, crz[nt], 0, 0, 0);
    }
  }
  #pragma unroll
  for (int nt = 0; nt < 4; ++nt) {
    #pragma unroll
    for (int ks = 0; ks < 2; ++ks) {
      bf16x8 bi = *(const bf16x8*)&Wih[(128 + nt * 16 + l) * 64 + ks * 32 + quad * 8];
      cni[nt] = __builtin_amdgcn_mfma_f32_16x16x32_bf16(ax[ks], bi, cni[nt], 0, 0, 0);
      bf16x8 bh = *(const bf16x8*)&Whh[(128 + nt * 16 + l) * 64 + ks * 32 + quad * 8];
      cnh[nt] = __builtin_amdgcn_mfma_f32_16x16x32_bf16(ah[ks], bh, cnh[nt], 0, 0, 0);
    }
  }

  // epilogue (C layout: row = quad*4+rg, col = t*16+l)
  const long grow = gr0 + r0 + quad * 4;
  float qp[4][NACT_];
  #pragma unroll
  for (int rg = 0; rg < 4; ++rg)
    #pragma unroll
    for (int c = 0; c < NACT_; ++c) qp[rg][c] = 0.0f;

  #pragma unroll
  for (int t = 0; t < 4; ++t) {
    const int ur = t * 16 + l;
    float br  = b_ih[ur] + b_hh[ur];
    float bz  = b_ih[64 + ur] + b_hh[64 + ur];
    float bin = b_ih[128 + ur], bhn = b_hh[128 + ur];
    float w0 = w_fc2[ur * 5 + 0], w1 = w_fc2[ur * 5 + 1], w2 = w_fc2[ur * 5 + 2];
    float w3 = w_fc2[ur * 5 + 3], w4 = w_fc2[ur * 5 + 4];
    #pragma unroll
    for (int rg = 0; rg < 4; ++rg) {
      float rr = sigmoidf(crz[t][rg] + br);
      float zz = sigmoidf(crz[4 + t][rg] + bz);
      float nn = tanh_fast(cni[t][rg] + bin + rr * (cnh[t][rg] + bhn));
      float hold = hidden[(grow + rg) * HID_ + ur];
      float hn = (1.0f - zz) * nn + zz * hold;
      h_out[(grow + rg) * HID_ + ur] = hn;
      qp[rg][0] += hn * w0;
      qp[rg][1] += hn * w1;
      qp[rg][2] += hn * w2;
      qp[rg][3] += hn * w3;
      qp[rg][4] += hn * w4;
    }
  }
  #pragma unroll
  for (int m = 1; m < 16; m <<= 1) {
    #pragma unroll
    for (int rg = 0; rg < 4; ++rg)
      #pragma unroll
      for (int c = 0; c < NACT_; ++c) qp[rg][c] += __shfl_xor(qp[rg][c], m, 64);
  }
  if (l < NACT_) {
    #pragma unroll
    for (int rg = 0; rg < 4; ++rg) {
      float qv = qp[rg][0];
      if (l == 1) qv = qp[rg][1];
      if (l == 2) qv = qp[rg][2];
      if (l == 3) qv = qp[rg][3];
      if (l == 4) qv = qp[rg][4];
      q5[(grow + rg) * NACT_ + l] = qv + b_fc2[l];
    }
  }
}

}  // namespace

extern "C" void kernel_launch(void* const* d_in, const int* in_sizes, int n_in,
                              void* d_out, int out_size, void* d_ws, size_t ws_size,
                              hipStream_t stream) {
  const float* obs    = (const float*)d_in[0];
  const float* hidden = (const float*)d_in[1];
  const float* w_in0  = (const float*)d_in[2];
  const float* b_in0  = (const float*)d_in[3];
  const float* w_in1  = (const float*)d_in[4];
  const float* b_in1  = (const float*)d_in[5];
  const float* w_in2  = (const float*)d_in[6];
  const float* b_in2  = (const float*)d_in[7];
  const float* W      = (const float*)d_in[8];
  const float* a      = (const float*)d_in[9];
  const float* w_o1   = (const float*)d_in[10];
  const float* b_o1   = (const float*)d_in[11];
  const float* w_o2   = (const float*)d_in[12];
  const float* b_o2   = (const float*)d_in[13];
  const float* w_o3   = (const float*)d_in[14];
  const float* b_o3   = (const float*)d_in[15];
  const float* w_fc1  = (const float*)d_in[16];
  const float* b_fc1  = (const float*)d_in[17];
  const float* w_ih   = (const float*)d_in[18];
  const float* w_hh   = (const float*)d_in[19];
  const float* b_ih   = (const float*)d_in[20];
  const float* b_hh   = (const float*)d_in[21];
  const float* w_fc2  = (const float*)d_in[22];
  const float* b_fc2  = (const float*)d_in[23];

  float* q_out = (float*)d_out;                  // (B,5) -- also obs_out scratch
  float* h_out = q_out + (long)B_ * NACT_;       // (B,64)
  const float* Wa = (const float*)d_ws;

  prep_kernel<<<48, 256, 0, stream>>>(W, a, w_ih, w_hh, w_fc1, d_ws);
  front_kernel<<<B_ / FROWS_, 256, 0, stream>>>(
      obs, w_in0, b_in0, w_in1, b_in1, w_in2, b_in2,
      w_o1, b_o1, w_o2, b_o2, w_o3, b_o3, Wa, q_out);
  gemm_kernel<<<B_ / ROWS_, 256, 0, stream>>>(
      obs, hidden, b_fc1, b_ih, b_hh, w_fc2, b_fc2, d_ws, q_out, h_out);
}